// Round 1
// 355.791 us; speedup vs baseline: 1.2209x; 1.2209x over previous
//
#include <hip/hip_runtime.h>
#include <cstdint>
#include <cstddef>

// ---------------------------------------------------------------------------
// COAMultiHeadAttention on gfx950: B=2, T=2048, D=1024, H=16, HD=64.
// detect -> cvt(bf16) -> 3x proj GEMM (128^2, global_load_lds, swizzled, dbuf)
//        -> mask-tile prepass -> V transpose -> flash attn (dbuf, swizzled)
//        -> out GEMM.
// ---------------------------------------------------------------------------

using frag8 = __attribute__((ext_vector_type(8))) short;   // 8 x bf16
using f32x4 = __attribute__((ext_vector_type(4))) float;   // MFMA accum
using int4v = __attribute__((ext_vector_type(4))) int;     // 16B vector

#define MFMA16(a, b, c) __builtin_amdgcn_mfma_f32_16x16x32_bf16((a), (b), (c), 0, 0, 0)

#define T_SEQ 2048
#define D_MOD 1024

__device__ __forceinline__ float bf2f(unsigned short s) {
    unsigned u = ((unsigned)s) << 16;
    return __builtin_bit_cast(float, u);
}
__device__ __forceinline__ short f2bf(float f) {
    unsigned u = __builtin_bit_cast(unsigned, f);
    u += 0x7fffu + ((u >> 16) & 1u);   // round-to-nearest-even
    return (short)(u >> 16);
}

// async global->LDS, 16B per lane. LDS dest = wave-uniform base + lane*16.
__device__ __forceinline__ void gload16(const void* g, void* l) {
    auto gp = (const __attribute__((address_space(1))) char*)(uintptr_t)(g);
    auto lp = (__attribute__((address_space(3))) char*)(uintptr_t)(l);
    __builtin_amdgcn_global_load_lds(
        (const __attribute__((address_space(1))) void*)gp,
        (__attribute__((address_space(3))) void*)lp, 16, 0, 0);
}

// ---------------------------------------------------------------------------
// Dtype detection (unchanged): f32 mantissa shorts show big bf16 exponents.
// ---------------------------------------------------------------------------
__global__ void detect_dtype(const unsigned short* __restrict__ q, int* __restrict__ flag) {
    if (threadIdx.x == 0) {
        int f = 0;
        for (int i = 0; i < 256; ++i) {
            const int e = (q[i] >> 7) & 0xFF;
            f |= (e >= 0xC0) ? 1 : 0;
        }
        *flag = f;   // 1 => external floats are f32, 0 => bf16
    }
}

// ---------------------------------------------------------------------------
// f32 -> bf16 conversion (only runs when dtype == f32; else early-out and
// the GEMMs read the external bf16 tensors directly).
// ---------------------------------------------------------------------------
__device__ __forceinline__ void cvt8(unsigned short* dst, const float* src) {
    float4 lo = *(const float4*)src;
    float4 hi = *(const float4*)(src + 4);
    union { int4v v; unsigned short s[8]; } pk;
    pk.s[0] = (unsigned short)f2bf(lo.x); pk.s[1] = (unsigned short)f2bf(lo.y);
    pk.s[2] = (unsigned short)f2bf(lo.z); pk.s[3] = (unsigned short)f2bf(lo.w);
    pk.s[4] = (unsigned short)f2bf(hi.x); pk.s[5] = (unsigned short)f2bf(hi.y);
    pk.s[6] = (unsigned short)f2bf(hi.z); pk.s[7] = (unsigned short)f2bf(hi.w);
    *(int4v*)dst = pk.v;
}

__global__ __launch_bounds__(256) void cvt_x(
    const float* __restrict__ q, const float* __restrict__ k, const float* __restrict__ v,
    unsigned short* __restrict__ xq, unsigned short* __restrict__ xk,
    unsigned short* __restrict__ xv, const int* __restrict__ dflag)
{
    if (dflag[0] == 0) return;
    const float* src = (blockIdx.y == 0) ? q : (blockIdx.y == 1) ? k : v;
    unsigned short* dst = (blockIdx.y == 0) ? xq : (blockIdx.y == 1) ? xk : xv;
    const size_t i = ((size_t)blockIdx.x * 256 + threadIdx.x) * 8;
    cvt8(dst + i, src + i);
}

__global__ __launch_bounds__(256) void cvt_w(
    const float* __restrict__ a, const float* __restrict__ b2,
    const float* __restrict__ c, const float* __restrict__ d,
    unsigned short* __restrict__ oa, unsigned short* __restrict__ ob,
    unsigned short* __restrict__ oc, unsigned short* __restrict__ od,
    const int* __restrict__ dflag)
{
    if (dflag[0] == 0) return;
    const float* src = (blockIdx.y == 0) ? a : (blockIdx.y == 1) ? b2
                     : (blockIdx.y == 2) ? c : d;
    unsigned short* dst = (blockIdx.y == 0) ? oa : (blockIdx.y == 1) ? ob
                        : (blockIdx.y == 2) ? oc : od;
    const size_t i = ((size_t)blockIdx.x * 256 + threadIdx.x) * 8;
    cvt8(dst + i, src + i);
}

// ---------------------------------------------------------------------------
// GEMM: Y[M,N] = X[M,K] @ W[N,K]^T + bias[N].  128x128 tile, BK=64,
// 4 waves each 64x64 (4x4 MFMA tiles). global_load_lds staging into
// XOR-swizzled LDS (pre-swizzled global source, rule #21), double-buffered
// with prefetch-before-compute (T3 minimum 2-phase), 1 barrier / K-step.
// ---------------------------------------------------------------------------
__global__ __launch_bounds__(256) void gemm128(
    const void* __restrict__ Xe, const unsigned short* __restrict__ Xc,
    const void* __restrict__ We, const unsigned short* __restrict__ Wc,
    const void* __restrict__ bias, void* __restrict__ Y,
    int M, int N, int K, const int* __restrict__ dflag, int x_ext, int y_ext)
{
    __shared__ short sA[2][128][64];
    __shared__ short sB[2][128][64];

    const int isf32 = dflag[0];
    const unsigned short* X = (x_ext && isf32) ? Xc : (const unsigned short*)Xe;
    const unsigned short* W = isf32 ? Wc : (const unsigned short*)We;

    const int tid = threadIdx.x;
    const int w   = tid >> 6;
    const int l   = tid & 63;
    const int g   = l >> 4;
    const int r   = l & 15;
    const int rx  = r & 7;
    const int m0  = blockIdx.y * 128;
    const int n0  = blockIdx.x * 128;
    const int wm  = (w >> 1) * 64;
    const int wn  = (w & 1) * 64;
    const int lr  = l >> 3;           // LDS row within 8-row DMA chunk
    const int lc  = (l & 7) ^ lr;     // pre-swizzled source 16B-chunk

    const unsigned short* xsrc = X + (size_t)(m0 + w * 32 + lr) * K + lc * 8;
    const unsigned short* wsrc = W + (size_t)(n0 + w * 32 + lr) * K + lc * 8;

    f32x4 acc[4][4] = {};

    // prologue: stage k0=0 into buffer 0
#pragma unroll
    for (int i = 0; i < 4; ++i) {
        gload16(xsrc + (size_t)(i * 8) * K, &sA[0][w * 32 + i * 8][0]);
        gload16(wsrc + (size_t)(i * 8) * K, &sB[0][w * 32 + i * 8][0]);
    }
    __syncthreads();

    int cur = 0;
    for (int k0 = 0; k0 < K; k0 += 64) {
        if (k0 + 64 < K) {             // prefetch next tile (overlaps compute)
            const int nx = cur ^ 1;
#pragma unroll
            for (int i = 0; i < 4; ++i) {
                gload16(xsrc + (size_t)(i * 8) * K + (k0 + 64), &sA[nx][w * 32 + i * 8][0]);
                gload16(wsrc + (size_t)(i * 8) * K + (k0 + 64), &sB[nx][w * 32 + i * 8][0]);
            }
        }
#pragma unroll
        for (int ks = 0; ks < 2; ++ks) {
            frag8 af[4], bfr[4];
#pragma unroll
            for (int mt = 0; mt < 4; ++mt)
                af[mt] = *(const frag8*)&sA[cur][wm + mt * 16 + r][((ks * 4 + g) ^ rx) * 8];
#pragma unroll
            for (int nt = 0; nt < 4; ++nt)
                bfr[nt] = *(const frag8*)&sB[cur][wn + nt * 16 + r][((ks * 4 + g) ^ rx) * 8];
#pragma unroll
            for (int mt = 0; mt < 4; ++mt)
#pragma unroll
                for (int nt = 0; nt < 4; ++nt)
                    acc[mt][nt] = MFMA16(af[mt], bfr[nt], acc[mt][nt]);
        }
        __syncthreads();   // drains prefetch vmcnt + protects cur buffer
        cur ^= 1;
    }

#pragma unroll
    for (int nt = 0; nt < 4; ++nt) {
        const int n = n0 + wn + nt * 16 + r;
        const float bv = isf32 ? ((const float*)bias)[n]
                               : bf2f(((const unsigned short*)bias)[n]);
#pragma unroll
        for (int mt = 0; mt < 4; ++mt) {
#pragma unroll
            for (int reg = 0; reg < 4; ++reg) {
                const int m = m0 + wm + mt * 16 + g * 4 + reg;
                const float val = acc[mt][nt][reg] + bv;
                if (y_ext && isf32)
                    ((float*)Y)[(size_t)m * N + n] = val;
                else
                    ((unsigned short*)Y)[(size_t)m * N + n] = (unsigned short)f2bf(val);
            }
        }
    }
}

// ---------------------------------------------------------------------------
// Mask prepass: flags[b][qt][kt] = 1 iff any zero in the 64x64 mask tile.
// ---------------------------------------------------------------------------
__global__ __launch_bounds__(256) void mask_tiles(const int* __restrict__ mask,
                                                  int* __restrict__ flags)
{
    __shared__ int f;
    const int tid = threadIdx.x;
    if (tid == 0) f = 0;
    __syncthreads();
    const int b = blockIdx.z, qt = blockIdx.y, kt = blockIdx.x;
    const int* base = mask + (size_t)b * T_SEQ * T_SEQ
                    + (size_t)(qt * 64 + (tid >> 2)) * T_SEQ + kt * 64 + (tid & 3) * 16;
    int any = 0;
#pragma unroll
    for (int j = 0; j < 4; ++j) {
        int4v v = *(const int4v*)(base + j * 4);
        any |= (v.x == 0) | (v.y == 0) | (v.z == 0) | (v.w == 0);
    }
    if (any) f = 1;
    __syncthreads();
    if (tid == 0) flags[((size_t)b * 32 + qt) * 32 + kt] = f;
}

// ---------------------------------------------------------------------------
// V transpose: Vt[(b*16+h)*64 + d][t] = Vp[b*T+t][h*64+d]  (bf16)
// ---------------------------------------------------------------------------
__global__ __launch_bounds__(256) void vtrans(
    const unsigned short* __restrict__ Vp, unsigned short* __restrict__ Vt)
{
    __shared__ unsigned short s[64][72];
    const int tid = threadIdx.x;
    const int r0 = tid >> 3;
    const int c0 = (tid & 7) * 8;
    const int t0 = blockIdx.x * 64;
    const int h  = blockIdx.y, b = blockIdx.z;
    const size_t base = (size_t)b * T_SEQ * D_MOD + (size_t)h * 64;

    *(int4v*)&s[r0][c0]      = *(const int4v*)&Vp[base + (size_t)(t0 + r0) * D_MOD + c0];
    *(int4v*)&s[r0 + 32][c0] = *(const int4v*)&Vp[base + (size_t)(t0 + r0 + 32) * D_MOD + c0];
    __syncthreads();

    union { int4v v; unsigned short u[8]; } o0, o1;
#pragma unroll
    for (int j = 0; j < 8; ++j) { o0.u[j] = s[c0 + j][r0]; o1.u[j] = s[c0 + j][r0 + 32]; }
    const size_t ob = (size_t)(b * 16 + h) * 64;
    *(int4v*)&Vt[(ob + r0) * T_SEQ + t0 + c0]      = o0.v;
    *(int4v*)&Vt[(ob + r0 + 32) * T_SEQ + t0 + c0] = o1.v;
}

// ---------------------------------------------------------------------------
// Flash attention. One block per (b, h, 64-row Q tile); 4 waves x 16 q-rows.
// K/V double-buffered via global_load_lds (swizzled), mask via tile flags,
// P routed through swizzled per-wave LDS scratch (unioned with dead sQ).
// LDS total = 40960 B -> 4 blocks/CU.
// ---------------------------------------------------------------------------
__global__ __launch_bounds__(256) void flash_attn(
    const unsigned short* __restrict__ Qp, const unsigned short* __restrict__ Kp,
    const unsigned short* __restrict__ Vt, const int* __restrict__ mask,
    const int* __restrict__ flags, unsigned short* __restrict__ att)
{
    __shared__ short sK[2][64][64];
    __shared__ short sV[2][64][64];     // sV[buf][d][k]
    __shared__ short sQP[4][16][64];    // Q tile (pre-loop), then per-wave P

    const int tid = threadIdx.x;
    const int w = tid >> 6;
    const int l = tid & 63;
    const int g = l >> 4;
    const int r = l & 15;
    const int rx = r & 7;
    const int b = blockIdx.z, h = blockIdx.y;
    const int q0 = blockIdx.x * 64;
    const int lr = l >> 3;
    const int lc = (l & 7) ^ lr;

    short (*sq)[64] = reinterpret_cast<short (*)[64]>(sQP);

    const size_t qkbase = (size_t)b * T_SEQ * D_MOD + (size_t)h * 64;
    const unsigned short* qsrc = Qp + qkbase + (size_t)(q0 + w * 16 + lr) * D_MOD + lc * 8;
    const unsigned short* ksrc = Kp + qkbase + (size_t)(w * 16 + lr) * D_MOD + lc * 8;
    const unsigned short* vsrc = Vt + (size_t)((b * 16 + h) * 64 + w * 16 + lr) * T_SEQ + lc * 8;

    // stage Q + first K/V tile
    gload16(qsrc,                         &sq[w * 16][0]);
    gload16(qsrc + (size_t)8 * D_MOD,     &sq[w * 16 + 8][0]);
    gload16(ksrc,                         &sK[0][w * 16][0]);
    gload16(ksrc + (size_t)8 * D_MOD,     &sK[0][w * 16 + 8][0]);
    gload16(vsrc,                         &sV[0][w * 16][0]);
    gload16(vsrc + (size_t)8 * T_SEQ,     &sV[0][w * 16 + 8][0]);
    __syncthreads();

    frag8 aq0 = *(const frag8*)&sq[w * 16 + r][(g ^ rx) * 8];
    frag8 aq1 = *(const frag8*)&sq[w * 16 + r][((4 + g) ^ rx) * 8];
    __syncthreads();   // sQ space is reused as sP from here on

    float run_m[4], run_l[4];
    f32x4 accO[4];
#pragma unroll
    for (int i = 0; i < 4; ++i) {
        run_m[i] = -1e30f;
        run_l[i] = 0.f;
        accO[i]  = f32x4{0.f, 0.f, 0.f, 0.f};
    }

    const float scale = 0.125f;  // 1/sqrt(64)
    const int* mrow = mask + (size_t)b * T_SEQ * T_SEQ;
    const int qrow = q0 + w * 16;
    const int* tfl = flags + ((size_t)b * 32 + (q0 >> 6)) * 32;

    int cur = 0;
    for (int kt = 0; kt < T_SEQ; kt += 64) {
        // prefetch next K/V tile (overlaps with this tile's compute)
        if (kt + 64 < T_SEQ) {
            const int nx = cur ^ 1;
            gload16(ksrc + (size_t)(kt + 64) * D_MOD,      &sK[nx][w * 16][0]);
            gload16(ksrc + (size_t)(kt + 72) * D_MOD,      &sK[nx][w * 16 + 8][0]);
            gload16(vsrc + (kt + 64),                      &sV[nx][w * 16][0]);
            gload16(vsrc + (size_t)8 * T_SEQ + (kt + 64),  &sV[nx][w * 16 + 8][0]);
        }

        // ---- S = Q K^T ----
        f32x4 s[4];
#pragma unroll
        for (int ct = 0; ct < 4; ++ct) {
            frag8 bk0 = *(const frag8*)&sK[cur][ct * 16 + r][(g ^ rx) * 8];
            frag8 bk1 = *(const frag8*)&sK[cur][ct * 16 + r][((4 + g) ^ rx) * 8];
            s[ct] = f32x4{0.f, 0.f, 0.f, 0.f};
            s[ct] = MFMA16(aq0, bk0, s[ct]);
            s[ct] = MFMA16(aq1, bk1, s[ct]);
        }

        // ---- mask + scale + tile row-max ----
        float p[4][4], tmax[4];
#pragma unroll
        for (int reg = 0; reg < 4; ++reg) tmax[reg] = -1e30f;

        const int tflag = tfl[kt >> 6];
        if (tflag == 0) {            // all-ones tile: no mask work
#pragma unroll
            for (int ct = 0; ct < 4; ++ct)
#pragma unroll
                for (int reg = 0; reg < 4; ++reg) {
                    const float v = s[ct][reg] * scale;
                    p[ct][reg] = v;
                    tmax[reg] = fmaxf(tmax[reg], v);
                }
        } else {                     // slow path: per-element mask
#pragma unroll
            for (int ct = 0; ct < 4; ++ct)
#pragma unroll
                for (int reg = 0; reg < 4; ++reg) {
                    float v = s[ct][reg] * scale;
                    const int mk = mrow[(size_t)(qrow + g * 4 + reg) * T_SEQ + kt + ct * 16 + r];
                    v = (mk == 0) ? -1e30f : v;
                    p[ct][reg] = v;
                    tmax[reg] = fmaxf(tmax[reg], v);
                }
        }
#pragma unroll
        for (int reg = 0; reg < 4; ++reg) {
            float t = tmax[reg];
            t = fmaxf(t, __shfl_xor(t, 1));
            t = fmaxf(t, __shfl_xor(t, 2));
            t = fmaxf(t, __shfl_xor(t, 4));
            t = fmaxf(t, __shfl_xor(t, 8));
            tmax[reg] = t;
        }

        // ---- online softmax update ----
        float alpha[4], rsum[4];
#pragma unroll
        for (int reg = 0; reg < 4; ++reg) {
            const float nm = fmaxf(run_m[reg], tmax[reg]);
            alpha[reg] = __expf(run_m[reg] - nm);
            run_m[reg] = nm;
            float srow = 0.f;
#pragma unroll
            for (int ct = 0; ct < 4; ++ct) {
                const float e = __expf(p[ct][reg] - nm);
                p[ct][reg] = e;
                srow += e;
            }
            rsum[reg] = srow;
        }
#pragma unroll
        for (int reg = 0; reg < 4; ++reg) {
            float t = rsum[reg];
            t += __shfl_xor(t, 1);
            t += __shfl_xor(t, 2);
            t += __shfl_xor(t, 4);
            t += __shfl_xor(t, 8);
            run_l[reg] = run_l[reg] * alpha[reg] + t;
        }

        // ---- P: C-layout regs -> swizzled per-wave LDS (bf16) ----
#pragma unroll
        for (int ct = 0; ct < 4; ++ct)
#pragma unroll
            for (int reg = 0; reg < 4; ++reg) {
                const int row = g * 4 + reg;
                const int col = ct * 16 + r;
                const int scol = (((col >> 3) ^ (row & 7)) << 3) | (col & 7);
                sQP[w][row][scol] = f2bf(p[ct][reg]);
            }

        // ---- O = alpha*O + P V ----
#pragma unroll
        for (int dt = 0; dt < 4; ++dt)
#pragma unroll
            for (int reg = 0; reg < 4; ++reg)
                accO[dt][reg] *= alpha[reg];

#pragma unroll
        for (int ks = 0; ks < 2; ++ks) {
            frag8 ap = *(const frag8*)&sQP[w][r][((ks * 4 + g) ^ rx) * 8];
#pragma unroll
            for (int dt = 0; dt < 4; ++dt) {
                frag8 bv = *(const frag8*)&sV[cur][dt * 16 + r][((ks * 4 + g) ^ rx) * 8];
                accO[dt] = MFMA16(ap, bv, accO[dt]);
            }
        }
        __syncthreads();   // drains prefetch + protects sK/sV[cur] for reuse
        cur ^= 1;
    }

    // ---- epilogue ----
#pragma unroll
    for (int dt = 0; dt < 4; ++dt) {
#pragma unroll
        for (int reg = 0; reg < 4; ++reg) {
            const float o = accO[dt][reg] / run_l[reg];
            const int qq = q0 + w * 16 + g * 4 + reg;
            att[((size_t)b * T_SEQ + qq) * D_MOD + h * 64 + dt * 16 + r] =
                (unsigned short)f2bf(o);
        }
    }
}

// ---------------------------------------------------------------------------
extern "C" void kernel_launch(void* const* d_in, const int* in_sizes, int n_in,
                              void* d_out, int out_size, void* d_ws, size_t ws_size,
                              hipStream_t stream) {
    const void* query = d_in[0];
    const void* key   = d_in[1];
    const void* value = d_in[2];
    const int*  mask  = (const int*)d_in[3];
    const void* wq = d_in[4];
    const void* bq = d_in[5];
    const void* wk = d_in[6];
    const void* bk = d_in[7];
    const void* wv = d_in[8];
    const void* bv = d_in[9];
    const void* wo = d_in[10];
    const void* bo = d_in[11];

    const int Mtot = 2 * T_SEQ;              // 4096
    const int D = D_MOD;                     // 1024
    const size_t MD = (size_t)Mtot * D;      // 4M elems
    const size_t WW = (size_t)D * D;         // 1M elems

    // ws layout (bf16 shorts), ~56 MB total:
    unsigned short* Xq  = (unsigned short*)d_ws;  // converted query; reused as Vt
    unsigned short* Xk  = Xq + MD;
    unsigned short* Xv  = Xk + MD;
    unsigned short* Wqb = Xv + MD;
    unsigned short* Wkb = Wqb + WW;
    unsigned short* Wvb = Wkb + WW;
    unsigned short* Wob = Wvb + WW;
    unsigned short* Qp  = Wob + WW;
    unsigned short* Kp  = Qp + MD;
    unsigned short* Vp  = Kp + MD;
    unsigned short* Vt  = Xq;                // alias: Xq dead after Q GEMM
    unsigned short* att = Vp;                // alias: Vp dead after vtrans
    int* flags          = (int*)(Vp + MD);   // 2048 ints
    int* dflag          = flags + 2048;

    const dim3 blk(256);
    const dim3 gg(D / 128, Mtot / 128);      // (8, 32)

    detect_dtype<<<1, 64, 0, stream>>>((const unsigned short*)query, dflag);

    cvt_x<<<dim3(2048, 3), blk, 0, stream>>>(
        (const float*)query, (const float*)key, (const float*)value, Xq, Xk, Xv, dflag);
    cvt_w<<<dim3(512, 4), blk, 0, stream>>>(
        (const float*)wq, (const float*)wk, (const float*)wv, (const float*)wo,
        Wqb, Wkb, Wvb, Wob, dflag);

    gemm128<<<gg, blk, 0, stream>>>(query, Xq, wq, Wqb, bq, Qp, Mtot, D, D, dflag, 1, 0);
    gemm128<<<gg, blk, 0, stream>>>(key,   Xk, wk, Wkb, bk, Kp, Mtot, D, D, dflag, 1, 0);
    gemm128<<<gg, blk, 0, stream>>>(value, Xv, wv, Wvb, bv, Vp, Mtot, D, D, dflag, 1, 0);

    mask_tiles<<<dim3(32, 32, 2), blk, 0, stream>>>(mask, flags);
    vtrans<<<dim3(32, 16, 2), blk, 0, stream>>>(Vp, Vt);

    flash_attn<<<dim3(T_SEQ / 64, 16, 2), blk, 0, stream>>>(Qp, Kp, Vt, mask, flags, att);

    gemm128<<<gg, blk, 0, stream>>>(att, att, wo, Wob, bo, d_out, Mtot, D, D, dflag, 0, 1);
}

// Round 3
// 277.130 us; speedup vs baseline: 1.5675x; 1.2838x over previous
//
#include <hip/hip_runtime.h>
#include <cstdint>
#include <cstddef>

// ---------------------------------------------------------------------------
// COAMultiHeadAttention on gfx950: B=2, T=2048, D=1024, H=16, HD=64.
// detect -> cvt(bf16) -> merged QKV GEMM (128^2, gload_lds, swizzled, dbuf)
//        -> vtrans -> mask prepass -> flash attn (32x32 swapped-QK^T,
//           in-register softmax, defer-max, shfl-based P redistribution)
//        -> out GEMM.
// ---------------------------------------------------------------------------

using frag8  = __attribute__((ext_vector_type(8))) short;   // 8 x bf16
using f32x4  = __attribute__((ext_vector_type(4))) float;
using f32x16 = __attribute__((ext_vector_type(16))) float;  // 32x32 MFMA accum
using int4v  = __attribute__((ext_vector_type(4))) int;     // 16B vector

#define MFMA16(a,b,c) __builtin_amdgcn_mfma_f32_16x16x32_bf16((a),(b),(c),0,0,0)
#define MFMA32(a,b,c) __builtin_amdgcn_mfma_f32_32x32x16_bf16((a),(b),(c),0,0,0)

#define T_SEQ 2048
#define D_MOD 1024
#define QSCALE 0.18033688011112042f   // 0.125 * log2(e): fold attn scale + exp2 domain into Q

__device__ __forceinline__ float bf2f(unsigned short s) {
    unsigned u = ((unsigned)s) << 16;
    return __builtin_bit_cast(float, u);
}
__device__ __forceinline__ short f2bf(float f) {
    unsigned u = __builtin_bit_cast(unsigned, f);
    u += 0x7fffu + ((u >> 16) & 1u);   // RNE
    return (short)(u >> 16);
}

// async global->LDS, 16B per lane. LDS dest = wave-uniform base + lane*16.
__device__ __forceinline__ void gload16(const void* g, void* l) {
    auto gp = (const __attribute__((address_space(1))) char*)(uintptr_t)(g);
    auto lp = (__attribute__((address_space(3))) char*)(uintptr_t)(l);
    __builtin_amdgcn_global_load_lds(
        (const __attribute__((address_space(1))) void*)gp,
        (__attribute__((address_space(3))) void*)lp, 16, 0, 0);
}

// hardware 2^x
__device__ __forceinline__ float exp2_hw(float x) {
    float r;
    asm("v_exp_f32 %0, %1" : "=v"(r) : "v"(x));
    return r;
}
// pack 2 f32 -> bf16x2 in one inst: D.lo = cvt(a), D.hi = cvt(b)
__device__ __forceinline__ unsigned cvtpk(float a, float b) {
    unsigned r;
    asm("v_cvt_pk_bf16_f32 %0, %1, %2" : "=v"(r) : "v"(a), "v"(b));
    return r;
}

// Cross-half exchange building PV A-frags (direction-unambiguous, via shfl):
//   hi=0 lane wants [own a0, own a1, partner a0, partner a1]
//   hi=1 lane wants [partner a2, partner a3, own a2, own a3]
// hi=0 sends a2,a3 (partner needs them); hi=1 sends a0,a1.
__device__ __forceinline__ void xhalf(unsigned& a0, unsigned& a1,
                                      unsigned& a2, unsigned& a3, const int hi) {
    const unsigned sA = hi ? a0 : a2;
    const unsigned sB = hi ? a1 : a3;
    const unsigned tA = __shfl_xor(sA, 32, 64);
    const unsigned tB = __shfl_xor(sB, 32, 64);
    a0 = hi ? tA : a0;
    a1 = hi ? tB : a1;
    a2 = hi ? a2 : tA;
    a3 = hi ? a3 : tB;
}

// ---------------------------------------------------------------------------
// Dtype detection: f32 data read as shorts shows large bf16 exponent fields.
// ---------------------------------------------------------------------------
__global__ void detect_dtype(const unsigned short* __restrict__ q, int* __restrict__ flag) {
    if (threadIdx.x == 0) {
        int f = 0;
        for (int i = 0; i < 256; ++i) {
            const int e = (q[i] >> 7) & 0xFF;
            f |= (e >= 0xC0) ? 1 : 0;
        }
        *flag = f;   // 1 => external floats are f32, 0 => bf16
    }
}

// ---------------------------------------------------------------------------
// f32 -> bf16 conversion (runs only when dtype == f32).
// ---------------------------------------------------------------------------
__device__ __forceinline__ void cvt8(unsigned short* dst, const float* src) {
    float4 lo = *(const float4*)src;
    float4 hi = *(const float4*)(src + 4);
    union { int4v v; unsigned short s[8]; } pk;
    pk.s[0] = (unsigned short)f2bf(lo.x); pk.s[1] = (unsigned short)f2bf(lo.y);
    pk.s[2] = (unsigned short)f2bf(lo.z); pk.s[3] = (unsigned short)f2bf(lo.w);
    pk.s[4] = (unsigned short)f2bf(hi.x); pk.s[5] = (unsigned short)f2bf(hi.y);
    pk.s[6] = (unsigned short)f2bf(hi.z); pk.s[7] = (unsigned short)f2bf(hi.w);
    *(int4v*)dst = pk.v;
}

__global__ __launch_bounds__(256) void cvt_x(
    const float* __restrict__ q, const float* __restrict__ k, const float* __restrict__ v,
    unsigned short* __restrict__ xq, unsigned short* __restrict__ xk,
    unsigned short* __restrict__ xv, const int* __restrict__ dflag)
{
    if (dflag[0] == 0) return;
    const float* src = (blockIdx.y == 0) ? q : (blockIdx.y == 1) ? k : v;
    unsigned short* dst = (blockIdx.y == 0) ? xq : (blockIdx.y == 1) ? xk : xv;
    const size_t i = ((size_t)blockIdx.x * 256 + threadIdx.x) * 8;
    cvt8(dst + i, src + i);
}

__global__ __launch_bounds__(256) void cvt_w(
    const float* __restrict__ a, const float* __restrict__ b2,
    const float* __restrict__ c, const float* __restrict__ d,
    unsigned short* __restrict__ oa, unsigned short* __restrict__ ob,
    unsigned short* __restrict__ oc, unsigned short* __restrict__ od,
    const int* __restrict__ dflag)
{
    if (dflag[0] == 0) return;
    const float* src = (blockIdx.y == 0) ? a : (blockIdx.y == 1) ? b2
                     : (blockIdx.y == 2) ? c : d;
    unsigned short* dst = (blockIdx.y == 0) ? oa : (blockIdx.y == 1) ? ob
                        : (blockIdx.y == 2) ? oc : od;
    const size_t i = ((size_t)blockIdx.x * 256 + threadIdx.x) * 8;
    cvt8(dst + i, src + i);
}

// ---------------------------------------------------------------------------
// GEMM body: Y tile at (m0,n0) = X[M,K] @ W[N,K]^T + bias, 128x128 tile,
// BK=64, 4 waves x (64x64). gload_lds into XOR-swizzled LDS, double-buffered.
// Epilogue: val = (acc + bias) * oscale.
// ---------------------------------------------------------------------------
__device__ __forceinline__ void gemm128_body(
    const unsigned short* __restrict__ X, const unsigned short* __restrict__ W,
    const void* __restrict__ bias, void* __restrict__ Y,
    const int N, const int K, const int isf32, const int y_f32, const float oscale,
    const int m0, const int n0)
{
    __shared__ short sA[2][128][64];
    __shared__ short sB[2][128][64];

    const int tid = threadIdx.x;
    const int w   = tid >> 6;
    const int l   = tid & 63;
    const int g   = l >> 4;
    const int r   = l & 15;
    const int rx  = r & 7;
    const int wm  = (w >> 1) * 64;
    const int wn  = (w & 1) * 64;
    const int lr  = l >> 3;
    const int lc  = (l & 7) ^ lr;     // pre-swizzled source chunk

    const unsigned short* xsrc = X + (size_t)(m0 + w * 32 + lr) * K + lc * 8;
    const unsigned short* wsrc = W + (size_t)(n0 + w * 32 + lr) * K + lc * 8;

    f32x4 acc[4][4] = {};

#pragma unroll
    for (int i = 0; i < 4; ++i) {
        gload16(xsrc + (size_t)(i * 8) * K, &sA[0][w * 32 + i * 8][0]);
        gload16(wsrc + (size_t)(i * 8) * K, &sB[0][w * 32 + i * 8][0]);
    }
    __syncthreads();

    int cur = 0;
    for (int k0 = 0; k0 < K; k0 += 64) {
        if (k0 + 64 < K) {
            const int nx = cur ^ 1;
#pragma unroll
            for (int i = 0; i < 4; ++i) {
                gload16(xsrc + (size_t)(i * 8) * K + (k0 + 64), &sA[nx][w * 32 + i * 8][0]);
                gload16(wsrc + (size_t)(i * 8) * K + (k0 + 64), &sB[nx][w * 32 + i * 8][0]);
            }
        }
#pragma unroll
        for (int ks = 0; ks < 2; ++ks) {
            frag8 af[4], bfr[4];
#pragma unroll
            for (int mt = 0; mt < 4; ++mt)
                af[mt] = *(const frag8*)&sA[cur][wm + mt * 16 + r][((ks * 4 + g) ^ rx) * 8];
#pragma unroll
            for (int nt = 0; nt < 4; ++nt)
                bfr[nt] = *(const frag8*)&sB[cur][wn + nt * 16 + r][((ks * 4 + g) ^ rx) * 8];
            __builtin_amdgcn_s_setprio(1);
#pragma unroll
            for (int mt = 0; mt < 4; ++mt)
#pragma unroll
                for (int nt = 0; nt < 4; ++nt)
                    acc[mt][nt] = MFMA16(af[mt], bfr[nt], acc[mt][nt]);
            __builtin_amdgcn_s_setprio(0);
        }
        __syncthreads();
        cur ^= 1;
    }

#pragma unroll
    for (int nt = 0; nt < 4; ++nt) {
        const int n = n0 + wn + nt * 16 + r;
        const float bv = isf32 ? ((const float*)bias)[n]
                               : bf2f(((const unsigned short*)bias)[n]);
#pragma unroll
        for (int mt = 0; mt < 4; ++mt) {
#pragma unroll
            for (int reg = 0; reg < 4; ++reg) {
                const int m = m0 + wm + mt * 16 + g * 4 + reg;
                const float val = (acc[mt][nt][reg] + bv) * oscale;
                if (y_f32)
                    ((float*)Y)[(size_t)m * N + n] = val;
                else
                    ((unsigned short*)Y)[(size_t)m * N + n] = (unsigned short)f2bf(val);
            }
        }
    }
}

// merged Q/K/V projection: blockIdx.z selects the tensor (768 blocks)
__global__ __launch_bounds__(256) void gemm_qkv(
    const void* q, const unsigned short* qc, const void* k, const unsigned short* kc,
    const void* v, const unsigned short* vc,
    const void* wq, const unsigned short* wqc, const void* wk, const unsigned short* wkc,
    const void* wv, const unsigned short* wvc,
    const void* bq, const void* bk, const void* bv,
    unsigned short* Qp, unsigned short* Kp, unsigned short* Vp,
    const int* __restrict__ dflag)
{
    const int isf32 = dflag[0];
    const int z = blockIdx.z;
    const unsigned short* X;
    const unsigned short* W;
    const void* B;
    unsigned short* Y;
    float sc;
    if (z == 0) {
        X = isf32 ? qc : (const unsigned short*)q;
        W = isf32 ? wqc : (const unsigned short*)wq;
        B = bq; Y = Qp; sc = QSCALE;
    } else if (z == 1) {
        X = isf32 ? kc : (const unsigned short*)k;
        W = isf32 ? wkc : (const unsigned short*)wk;
        B = bk; Y = Kp; sc = 1.0f;
    } else {
        X = isf32 ? vc : (const unsigned short*)v;
        W = isf32 ? wvc : (const unsigned short*)wv;
        B = bv; Y = Vp; sc = 1.0f;
    }
    gemm128_body(X, W, B, Y, D_MOD, D_MOD, isf32, 0, sc,
                 blockIdx.y * 128, blockIdx.x * 128);
}

__global__ __launch_bounds__(256) void gemm_out(
    const unsigned short* __restrict__ att, const void* wo, const unsigned short* woc,
    const void* bo, void* out, const int* __restrict__ dflag)
{
    const int isf32 = dflag[0];
    const unsigned short* W = isf32 ? woc : (const unsigned short*)wo;
    gemm128_body(att, W, bo, out, D_MOD, D_MOD, isf32, isf32, 1.0f,
                 blockIdx.y * 128, blockIdx.x * 128);
}

// ---------------------------------------------------------------------------
// Mask prepass: flags[b][qt][kt] = 1 iff any zero in the 64x64 mask tile.
// ---------------------------------------------------------------------------
__global__ __launch_bounds__(256) void mask_tiles(const int* __restrict__ mask,
                                                  int* __restrict__ flags)
{
    __shared__ int f;
    const int tid = threadIdx.x;
    if (tid == 0) f = 0;
    __syncthreads();
    const int b = blockIdx.z, qt = blockIdx.y, kt = blockIdx.x;
    const int* base = mask + (size_t)b * T_SEQ * T_SEQ
                    + (size_t)(qt * 64 + (tid >> 2)) * T_SEQ + kt * 64 + (tid & 3) * 16;
    int any = 0;
#pragma unroll
    for (int j = 0; j < 4; ++j) {
        int4v v = *(const int4v*)(base + j * 4);
        any |= (v.x == 0) | (v.y == 0) | (v.z == 0) | (v.w == 0);
    }
    if (any) f = 1;
    __syncthreads();
    if (tid == 0) flags[((size_t)b * 32 + qt) * 32 + kt] = f;
}

// ---------------------------------------------------------------------------
// V transpose: Vt[(b*16+h)*64 + d][t] = Vp[b*T+t][h*64+d]  (bf16)
// ---------------------------------------------------------------------------
__global__ __launch_bounds__(256) void vtrans(
    const unsigned short* __restrict__ Vp, unsigned short* __restrict__ Vt)
{
    __shared__ unsigned short s[64][72];
    const int tid = threadIdx.x;
    const int r0 = tid >> 3;
    const int c0 = (tid & 7) * 8;
    const int t0 = blockIdx.x * 64;
    const int h  = blockIdx.y, b = blockIdx.z;
    const size_t base = (size_t)b * T_SEQ * D_MOD + (size_t)h * 64;

    *(int4v*)&s[r0][c0]      = *(const int4v*)&Vp[base + (size_t)(t0 + r0) * D_MOD + c0];
    *(int4v*)&s[r0 + 32][c0] = *(const int4v*)&Vp[base + (size_t)(t0 + r0 + 32) * D_MOD + c0];
    __syncthreads();

    union { int4v v; unsigned short u[8]; } o0, o1;
#pragma unroll
    for (int j = 0; j < 8; ++j) { o0.u[j] = s[c0 + j][r0]; o1.u[j] = s[c0 + j][r0 + 32]; }
    const size_t ob = (size_t)(b * 16 + h) * 64;
    *(int4v*)&Vt[(ob + r0) * T_SEQ + t0 + c0]      = o0.v;
    *(int4v*)&Vt[(ob + r0 + 32) * T_SEQ + t0 + c0] = o1.v;
}

// ---------------------------------------------------------------------------
// Flash attention, 32x32 swapped-QK^T structure.
// Block = 4 waves x 32 q-rows = 128 q; grid (16,16,2) = 512 blocks (2/CU).
// Lane owns one q-row of S (col = lane&31); softmax fully in-register;
// P -> A-frags via cvt_pk + shfl_xor(32) cross-half exchange; defer-max
// rescale (THR = 8, log2 domain). K/V double-buffered via gload_lds with
// XOR swizzle. Q in registers (scale pre-folded by QSCALE in the Q GEMM).
// ---------------------------------------------------------------------------
__global__ __launch_bounds__(256) void flash_attn(
    const unsigned short* __restrict__ Qp, const unsigned short* __restrict__ Kp,
    const unsigned short* __restrict__ Vt, const int* __restrict__ mask,
    const int* __restrict__ flags, unsigned short* __restrict__ att)
{
    __shared__ short sK[2][64][64];
    __shared__ short sV[2][64][64];     // [buf][d][k]

    const int tid = threadIdx.x;
    const int w   = tid >> 6;
    const int l   = tid & 63;
    const int lq  = l & 31;             // frag row / S column (this lane's q)
    const int hi  = l >> 5;
    const int lx  = lq & 7;             // read-side swizzle key
    const int b = blockIdx.z, h = blockIdx.y;
    const int q0 = blockIdx.x * 128;
    const int qw = q0 + w * 32;
    const int r0 = tid >> 3;            // staging row 0..31
    const int c0 = tid & 7;
    const int sc = c0 ^ (r0 & 7);       // pre-swizzled source chunk

    const size_t qkbase = (size_t)b * T_SEQ * D_MOD + (size_t)h * 64;
    const unsigned short* ksrc = Kp + qkbase + (size_t)r0 * D_MOD + sc * 8;
    const unsigned short* vsrc = Vt + ((size_t)((b * 16 + h) * 64) + r0) * T_SEQ + sc * 8;

#define STAGE_KV(buf, ktv)                                                        \
    {                                                                             \
        gload16(ksrc + (size_t)(ktv) * D_MOD,        &sK[buf][r0][c0 * 8]);       \
        gload16(ksrc + (size_t)((ktv) + 32) * D_MOD, &sK[buf][r0 + 32][c0 * 8]);  \
        gload16(vsrc + (ktv),                        &sV[buf][r0][c0 * 8]);       \
        gload16(vsrc + (size_t)32 * T_SEQ + (ktv),   &sV[buf][r0 + 32][c0 * 8]);  \
    }

    // Q fragments straight from global (L2-hot), B-layout: row lq, hd-slice
    frag8 qf[4];
    {
        const unsigned short* qrow = Qp + qkbase + (size_t)(qw + lq) * D_MOD + hi * 8;
#pragma unroll
        for (int ks = 0; ks < 4; ++ks)
            qf[ks] = *(const frag8*)(qrow + ks * 16);
    }

    STAGE_KV(0, 0);
    __syncthreads();

    float run_m = -1e30f, run_l = 0.f;
    f32x16 accO0 = {}, accO1 = {};

    const int* tfl = flags + ((size_t)b * 32 + (qw >> 6)) * 32;
    const int* mq  = mask + ((size_t)b * T_SEQ + qw + lq) * T_SEQ;

    int cur = 0;
    for (int kt = 0; kt < T_SEQ; kt += 64) {
        if (kt + 64 < T_SEQ) STAGE_KV(cur ^ 1, kt + 64);

        // ---- S^T = K Q^T : C[k][q], lane holds 32 S values of one q-row ----
        f32x16 s0 = {}, s1 = {};
        __builtin_amdgcn_s_setprio(1);
#pragma unroll
        for (int ks = 0; ks < 4; ++ks) {
            const int ch = ((ks * 2 + hi) ^ lx) * 8;
            frag8 k0 = *(const frag8*)&sK[cur][lq][ch];
            frag8 k1 = *(const frag8*)&sK[cur][32 + lq][ch];
            s0 = MFMA32(k0, qf[ks], s0);
            s1 = MFMA32(k1, qf[ks], s1);
        }
        __builtin_amdgcn_s_setprio(0);

        // ---- mask (slow path only) ----
        if (tfl[kt >> 6]) {
            const int* m0p = mq + kt;
#pragma unroll
            for (int r = 0; r < 16; ++r) {
                const int kof = (r & 3) + 8 * (r >> 2) + 4 * hi;
                if (m0p[kof] == 0)      s0[r] = -1e30f;
                if (m0p[32 + kof] == 0) s1[r] = -1e30f;
            }
        }

        // ---- tile max (in-lane tree + one cross-half exchange) ----
        float tm = s0[0];
#pragma unroll
        for (int r = 1; r < 16; ++r) tm = fmaxf(tm, s0[r]);
#pragma unroll
        for (int r = 0; r < 16; ++r) tm = fmaxf(tm, s1[r]);
        tm = fmaxf(tm, __shfl_xor(tm, 32, 64));

        // ---- defer-max rescale (rare after first tile) ----
        if (__any(tm > run_m + 8.0f)) {
            const float nm = fmaxf(run_m, tm);
            const float al = exp2_hw(run_m - nm);
            run_m = nm;
            run_l *= al;
            float alr[16];
#pragma unroll
            for (int r = 0; r < 16; ++r)
                alr[r] = __shfl(al, (r & 3) + 8 * (r >> 2) + 4 * hi, 64);
#pragma unroll
            for (int r = 0; r < 16; ++r) { accO0[r] *= alr[r]; accO1[r] *= alr[r]; }
        }

        // ---- exp2 + row sum ----
        float a0 = 0.f, a1 = 0.f, a2 = 0.f, a3 = 0.f;
#pragma unroll
        for (int r = 0; r < 16; r += 4) {
            s0[r]     = exp2_hw(s0[r]     - run_m);
            s0[r + 1] = exp2_hw(s0[r + 1] - run_m);
            s0[r + 2] = exp2_hw(s0[r + 2] - run_m);
            s0[r + 3] = exp2_hw(s0[r + 3] - run_m);
            s1[r]     = exp2_hw(s1[r]     - run_m);
            s1[r + 1] = exp2_hw(s1[r + 1] - run_m);
            s1[r + 2] = exp2_hw(s1[r + 2] - run_m);
            s1[r + 3] = exp2_hw(s1[r + 3] - run_m);
            a0 += s0[r]     + s1[r];
            a1 += s0[r + 1] + s1[r + 1];
            a2 += s0[r + 2] + s1[r + 2];
            a3 += s0[r + 3] + s1[r + 3];
        }
        float rs = (a0 + a1) + (a2 + a3);
        rs += __shfl_xor(rs, 32, 64);
        run_l += rs;

        // ---- P -> PV A-frags ----
        // C-layout gives (hi=0): s0[0..7] = k{0..3,8..11}; (hi=1): k{4..7,12..15}.
        // Pack pairs with cvt_pk, then exchange across the lane-32 halves so
        // each lane holds the A-frag k = ks*16 + hi*8 + {0..7}.
        union PU { frag8 f; unsigned u[4]; };
        PU pu0, pu1, pu2, pu3;
        pu0.u[0] = cvtpk(s0[0],  s0[1]);  pu0.u[1] = cvtpk(s0[2],  s0[3]);
        pu0.u[2] = cvtpk(s0[4],  s0[5]);  pu0.u[3] = cvtpk(s0[6],  s0[7]);
        pu1.u[0] = cvtpk(s0[8],  s0[9]);  pu1.u[1] = cvtpk(s0[10], s0[11]);
        pu1.u[2] = cvtpk(s0[12], s0[13]); pu1.u[3] = cvtpk(s0[14], s0[15]);
        pu2.u[0] = cvtpk(s1[0],  s1[1]);  pu2.u[1] = cvtpk(s1[2],  s1[3]);
        pu2.u[2] = cvtpk(s1[4],  s1[5]);  pu2.u[3] = cvtpk(s1[6],  s1[7]);
        pu3.u[0] = cvtpk(s1[8],  s1[9]);  pu3.u[1] = cvtpk(s1[10], s1[11]);
        pu3.u[2] = cvtpk(s1[12], s1[13]); pu3.u[3] = cvtpk(s1[14], s1[15]);
        xhalf(pu0.u[0], pu0.u[1], pu0.u[2], pu0.u[3], hi);
        xhalf(pu1.u[0], pu1.u[1], pu1.u[2], pu1.u[3], hi);
        xhalf(pu2.u[0], pu2.u[1], pu2.u[2], pu2.u[3], hi);
        xhalf(pu3.u[0], pu3.u[1], pu3.u[2], pu3.u[3], hi);
        frag8 pa[4] = { pu0.f, pu1.f, pu2.f, pu3.f };

        // ---- O += P V ----
        __builtin_amdgcn_s_setprio(1);
#pragma unroll
        for (int ks = 0; ks < 4; ++ks) {
            const int ch = ((ks * 2 + hi) ^ lx) * 8;
            frag8 v0 = *(const frag8*)&sV[cur][lq][ch];
            frag8 v1 = *(const frag8*)&sV[cur][32 + lq][ch];
            accO0 = MFMA32(pa[ks], v0, accO0);
            accO1 = MFMA32(pa[ks], v1, accO1);
        }
        __builtin_amdgcn_s_setprio(0);

        __syncthreads();   // drains prefetch; protects buffers
        cur ^= 1;
    }

    // ---- epilogue: O / l, gather per-row 1/l across lanes ----
    const float rinv = 1.0f / run_l;
    float rr[16];
#pragma unroll
    for (int r = 0; r < 16; ++r)
        rr[r] = __shfl(rinv, (r & 3) + 8 * (r >> 2) + 4 * hi, 64);
#pragma unroll
    for (int r = 0; r < 16; ++r) {
        const int qq = qw + (r & 3) + 8 * (r >> 2) + 4 * hi;
        unsigned short* orow = att + ((size_t)b * T_SEQ + qq) * D_MOD + h * 64 + lq;
        orow[0]  = (unsigned short)f2bf(accO0[r] * rr[r]);
        orow[32] = (unsigned short)f2bf(accO1[r] * rr[r]);
    }
#undef STAGE_KV
}

// ---------------------------------------------------------------------------
extern "C" void kernel_launch(void* const* d_in, const int* in_sizes, int n_in,
                              void* d_out, int out_size, void* d_ws, size_t ws_size,
                              hipStream_t stream) {
    const void* query = d_in[0];
    const void* key   = d_in[1];
    const void* value = d_in[2];
    const int*  mask  = (const int*)d_in[3];
    const void* wq = d_in[4];
    const void* bq = d_in[5];
    const void* wk = d_in[6];
    const void* bk = d_in[7];
    const void* wv = d_in[8];
    const void* bv = d_in[9];
    const void* wo = d_in[10];
    const void* bo = d_in[11];

    const int Mtot = 2 * T_SEQ;              // 4096
    const size_t MD = (size_t)Mtot * D_MOD;  // 4M elems
    const size_t WW = (size_t)D_MOD * D_MOD; // 1M elems

    unsigned short* Xq  = (unsigned short*)d_ws;  // converted query; reused as Vt
    unsigned short* Xk  = Xq + MD;
    unsigned short* Xv  = Xk + MD;
    unsigned short* Wqb = Xv + MD;
    unsigned short* Wkb = Wqb + WW;
    unsigned short* Wvb = Wkb + WW;
    unsigned short* Wob = Wvb + WW;
    unsigned short* Qp  = Wob + WW;
    unsigned short* Kp  = Qp + MD;
    unsigned short* Vp  = Kp + MD;
    unsigned short* Vt  = Xq;                // alias: Xq dead after Q GEMM
    unsigned short* att = Vp;                // alias: Vp dead after vtrans
    int* flags          = (int*)(Vp + MD);   // 2048 ints
    int* dflag          = flags + 2048;

    const dim3 blk(256);

    detect_dtype<<<1, 64, 0, stream>>>((const unsigned short*)query, dflag);

    cvt_x<<<dim3(2048, 3), blk, 0, stream>>>(
        (const float*)query, (const float*)key, (const float*)value, Xq, Xk, Xv, dflag);
    cvt_w<<<dim3(512, 4), blk, 0, stream>>>(
        (const float*)wq, (const float*)wk, (const float*)wv, (const float*)wo,
        Wqb, Wkb, Wvb, Wob, dflag);
    mask_tiles<<<dim3(32, 32, 2), blk, 0, stream>>>(mask, flags);

    gemm_qkv<<<dim3(D_MOD / 128, Mtot / 128, 3), blk, 0, stream>>>(
        query, Xq, key, Xk, value, Xv,
        wq, Wqb, wk, Wkb, wv, Wvb,
        bq, bk, bv, Qp, Kp, Vp, dflag);

    vtrans<<<dim3(32, 16, 2), blk, 0, stream>>>(Vp, Vt);

    flash_attn<<<dim3(T_SEQ / 128, 16, 2), blk, 0, stream>>>(Qp, Kp, Vt, mask, flags, att);

    gemm_out<<<dim3(D_MOD / 128, Mtot / 128), blk, 0, stream>>>(
        att, wo, Wob, bo, d_out, dflag);
}

// Round 4
// 273.944 us; speedup vs baseline: 1.5857x; 1.0116x over previous
//
#include <hip/hip_runtime.h>
#include <cstdint>
#include <cstddef>

// ---------------------------------------------------------------------------
// COAMultiHeadAttention on gfx950: B=2, T=2048, D=1024, H=16, HD=64.
// detect -> cvt(bf16) -> merged QKV GEMM (64x128 tile, gload_lds, swizzled,
//           dbuf, 3 blocks/CU) -> vtrans -> mask prepass -> flash attn
//           (32x32 swapped-QK^T, in-register softmax, defer-max) -> out GEMM.
// ---------------------------------------------------------------------------

using frag8  = __attribute__((ext_vector_type(8))) short;   // 8 x bf16
using f32x4  = __attribute__((ext_vector_type(4))) float;
using f32x16 = __attribute__((ext_vector_type(16))) float;  // 32x32 MFMA accum
using int4v  = __attribute__((ext_vector_type(4))) int;     // 16B vector

#define MFMA16(a,b,c) __builtin_amdgcn_mfma_f32_16x16x32_bf16((a),(b),(c),0,0,0)
#define MFMA32(a,b,c) __builtin_amdgcn_mfma_f32_32x32x16_bf16((a),(b),(c),0,0,0)

#define T_SEQ 2048
#define D_MOD 1024
#define QSCALE 0.18033688011112042f   // 0.125 * log2(e): fold attn scale + exp2 domain into Q

__device__ __forceinline__ float bf2f(unsigned short s) {
    unsigned u = ((unsigned)s) << 16;
    return __builtin_bit_cast(float, u);
}
__device__ __forceinline__ short f2bf(float f) {
    unsigned u = __builtin_bit_cast(unsigned, f);
    u += 0x7fffu + ((u >> 16) & 1u);   // RNE
    return (short)(u >> 16);
}

// async global->LDS, 16B per lane. LDS dest = wave-uniform base + lane*16.
__device__ __forceinline__ void gload16(const void* g, void* l) {
    auto gp = (const __attribute__((address_space(1))) char*)(uintptr_t)(g);
    auto lp = (__attribute__((address_space(3))) char*)(uintptr_t)(l);
    __builtin_amdgcn_global_load_lds(
        (const __attribute__((address_space(1))) void*)gp,
        (__attribute__((address_space(3))) void*)lp, 16, 0, 0);
}

// hardware 2^x
__device__ __forceinline__ float exp2_hw(float x) {
    float r;
    asm("v_exp_f32 %0, %1" : "=v"(r) : "v"(x));
    return r;
}
// pack 2 f32 -> bf16x2 in one inst: D.lo = cvt(a), D.hi = cvt(b)
__device__ __forceinline__ unsigned cvtpk(float a, float b) {
    unsigned r;
    asm("v_cvt_pk_bf16_f32 %0, %1, %2" : "=v"(r) : "v"(a), "v"(b));
    return r;
}

// Cross-half exchange building PV A-frags (direction-unambiguous, via shfl):
//   hi=0 lane wants [own a0, own a1, partner a0, partner a1]
//   hi=1 lane wants [partner a2, partner a3, own a2, own a3]
// hi=0 sends a2,a3 (partner needs them); hi=1 sends a0,a1.
__device__ __forceinline__ void xhalf(unsigned& a0, unsigned& a1,
                                      unsigned& a2, unsigned& a3, const int hi) {
    const unsigned sA = hi ? a0 : a2;
    const unsigned sB = hi ? a1 : a3;
    const unsigned tA = __shfl_xor(sA, 32, 64);
    const unsigned tB = __shfl_xor(sB, 32, 64);
    a0 = hi ? tA : a0;
    a1 = hi ? tB : a1;
    a2 = hi ? a2 : tA;
    a3 = hi ? a3 : tB;
}

// ---------------------------------------------------------------------------
// Dtype detection: f32 data read as shorts shows large bf16 exponent fields.
// ---------------------------------------------------------------------------
__global__ void detect_dtype(const unsigned short* __restrict__ q, int* __restrict__ flag) {
    if (threadIdx.x == 0) {
        int f = 0;
        for (int i = 0; i < 256; ++i) {
            const int e = (q[i] >> 7) & 0xFF;
            f |= (e >= 0xC0) ? 1 : 0;
        }
        *flag = f;   // 1 => external floats are f32, 0 => bf16
    }
}

// ---------------------------------------------------------------------------
// f32 -> bf16 conversion (runs only when dtype == f32).
// ---------------------------------------------------------------------------
__device__ __forceinline__ void cvt8(unsigned short* dst, const float* src) {
    float4 lo = *(const float4*)src;
    float4 hi = *(const float4*)(src + 4);
    union { int4v v; unsigned short s[8]; } pk;
    pk.s[0] = (unsigned short)f2bf(lo.x); pk.s[1] = (unsigned short)f2bf(lo.y);
    pk.s[2] = (unsigned short)f2bf(lo.z); pk.s[3] = (unsigned short)f2bf(lo.w);
    pk.s[4] = (unsigned short)f2bf(hi.x); pk.s[5] = (unsigned short)f2bf(hi.y);
    pk.s[6] = (unsigned short)f2bf(hi.z); pk.s[7] = (unsigned short)f2bf(hi.w);
    *(int4v*)dst = pk.v;
}

__global__ __launch_bounds__(256) void cvt_x(
    const float* __restrict__ q, const float* __restrict__ k, const float* __restrict__ v,
    unsigned short* __restrict__ xq, unsigned short* __restrict__ xk,
    unsigned short* __restrict__ xv, const int* __restrict__ dflag)
{
    if (dflag[0] == 0) return;
    const float* src = (blockIdx.y == 0) ? q : (blockIdx.y == 1) ? k : v;
    unsigned short* dst = (blockIdx.y == 0) ? xq : (blockIdx.y == 1) ? xk : xv;
    const size_t i = ((size_t)blockIdx.x * 256 + threadIdx.x) * 8;
    cvt8(dst + i, src + i);
}

__global__ __launch_bounds__(256) void cvt_w(
    const float* __restrict__ a, const float* __restrict__ b2,
    const float* __restrict__ c, const float* __restrict__ d,
    unsigned short* __restrict__ oa, unsigned short* __restrict__ ob,
    unsigned short* __restrict__ oc, unsigned short* __restrict__ od,
    const int* __restrict__ dflag)
{
    if (dflag[0] == 0) return;
    const float* src = (blockIdx.y == 0) ? a : (blockIdx.y == 1) ? b2
                     : (blockIdx.y == 2) ? c : d;
    unsigned short* dst = (blockIdx.y == 0) ? oa : (blockIdx.y == 1) ? ob
                        : (blockIdx.y == 2) ? oc : od;
    const size_t i = ((size_t)blockIdx.x * 256 + threadIdx.x) * 8;
    cvt8(dst + i, src + i);
}

// ---------------------------------------------------------------------------
// GEMM body: Y tile at (m0,n0) = X[M,K] @ W[N,K]^T + bias.
// Tile 64(M) x 128(N) x BK=64; 4 waves as 2Mx2N, each 32x64 (2x4 MFMA tiles).
// LDS 48KB -> 3 blocks/CU. gload_lds into XOR-swizzled LDS, double-buffered,
// 1 barrier / K-step. Epilogue: val = (acc + bias) * oscale.
// ---------------------------------------------------------------------------
__device__ __forceinline__ void gemm_body(
    const unsigned short* __restrict__ X, const unsigned short* __restrict__ W,
    const void* __restrict__ bias, void* __restrict__ Y,
    const int N, const int K, const int isf32, const int y_f32, const float oscale,
    const int m0, const int n0)
{
    __shared__ short sA[2][64][64];     // 16 KB
    __shared__ short sB[2][128][64];    // 32 KB

    const int tid = threadIdx.x;
    const int w   = tid >> 6;
    const int l   = tid & 63;
    const int g   = l >> 4;
    const int r   = l & 15;
    const int rx  = r & 7;
    const int wm  = (w >> 1) * 32;
    const int wn  = (w & 1) * 64;
    const int lr  = l >> 3;           // 0..7: row within 8-row DMA chunk
    const int lc  = (l & 7) ^ lr;     // pre-swizzled source chunk (row&7 key)

    // wave w stages A rows [w*16, w*16+16), B rows [w*32, w*32+32);
    // all sub-load row offsets are multiples of 8 -> swizzle key row&7 invariant.
    const unsigned short* xsrc = X + (size_t)(m0 + w * 16 + lr) * K + lc * 8;
    const unsigned short* wsrc = W + (size_t)(n0 + w * 32 + lr) * K + lc * 8;

    f32x4 acc[2][4] = {};

#define STAGE_AB(buf, kofs)                                                       \
    {                                                                             \
        gload16(xsrc + (size_t)0 * K  + (kofs), &sA[buf][w * 16][0]);             \
        gload16(xsrc + (size_t)8 * K  + (kofs), &sA[buf][w * 16 + 8][0]);         \
        gload16(wsrc + (size_t)0 * K  + (kofs), &sB[buf][w * 32][0]);             \
        gload16(wsrc + (size_t)8 * K  + (kofs), &sB[buf][w * 32 + 8][0]);         \
        gload16(wsrc + (size_t)16 * K + (kofs), &sB[buf][w * 32 + 16][0]);        \
        gload16(wsrc + (size_t)24 * K + (kofs), &sB[buf][w * 32 + 24][0]);        \
    }

    STAGE_AB(0, 0);
    __syncthreads();

    int cur = 0;
    for (int k0 = 0; k0 < K; k0 += 64) {
        if (k0 + 64 < K) STAGE_AB(cur ^ 1, k0 + 64);
#pragma unroll
        for (int ks = 0; ks < 2; ++ks) {
            frag8 af[2], bfr[4];
#pragma unroll
            for (int mt = 0; mt < 2; ++mt)
                af[mt] = *(const frag8*)&sA[cur][wm + mt * 16 + r][((ks * 4 + g) ^ rx) * 8];
#pragma unroll
            for (int nt = 0; nt < 4; ++nt)
                bfr[nt] = *(const frag8*)&sB[cur][wn + nt * 16 + r][((ks * 4 + g) ^ rx) * 8];
            __builtin_amdgcn_s_setprio(1);
#pragma unroll
            for (int mt = 0; mt < 2; ++mt)
#pragma unroll
                for (int nt = 0; nt < 4; ++nt)
                    acc[mt][nt] = MFMA16(af[mt], bfr[nt], acc[mt][nt]);
            __builtin_amdgcn_s_setprio(0);
        }
        __syncthreads();
        cur ^= 1;
    }
#undef STAGE_AB

#pragma unroll
    for (int nt = 0; nt < 4; ++nt) {
        const int n = n0 + wn + nt * 16 + r;
        const float bv = isf32 ? ((const float*)bias)[n]
                               : bf2f(((const unsigned short*)bias)[n]);
#pragma unroll
        for (int mt = 0; mt < 2; ++mt) {
#pragma unroll
            for (int reg = 0; reg < 4; ++reg) {
                const int m = m0 + wm + mt * 16 + g * 4 + reg;
                const float val = (acc[mt][nt][reg] + bv) * oscale;
                if (y_f32)
                    ((float*)Y)[(size_t)m * N + n] = val;
                else
                    ((unsigned short*)Y)[(size_t)m * N + n] = (unsigned short)f2bf(val);
            }
        }
    }
}

// merged Q/K/V projection: blockIdx.z selects the tensor (1536 blocks, 3/CU)
__global__ __launch_bounds__(256) void gemm_qkv(
    const void* q, const unsigned short* qc, const void* k, const unsigned short* kc,
    const void* v, const unsigned short* vc,
    const void* wq, const unsigned short* wqc, const void* wk, const unsigned short* wkc,
    const void* wv, const unsigned short* wvc,
    const void* bq, const void* bk, const void* bv,
    unsigned short* Qp, unsigned short* Kp, unsigned short* Vp,
    const int* __restrict__ dflag)
{
    const int isf32 = dflag[0];
    const int z = blockIdx.z;
    const unsigned short* X;
    const unsigned short* W;
    const void* B;
    unsigned short* Y;
    float sc;
    if (z == 0) {
        X = isf32 ? qc : (const unsigned short*)q;
        W = isf32 ? wqc : (const unsigned short*)wq;
        B = bq; Y = Qp; sc = QSCALE;
    } else if (z == 1) {
        X = isf32 ? kc : (const unsigned short*)k;
        W = isf32 ? wkc : (const unsigned short*)wk;
        B = bk; Y = Kp; sc = 1.0f;
    } else {
        X = isf32 ? vc : (const unsigned short*)v;
        W = isf32 ? wvc : (const unsigned short*)wv;
        B = bv; Y = Vp; sc = 1.0f;
    }
    gemm_body(X, W, B, Y, D_MOD, D_MOD, isf32, 0, sc,
              blockIdx.y * 64, blockIdx.x * 128);
}

__global__ __launch_bounds__(256) void gemm_out(
    const unsigned short* __restrict__ att, const void* wo, const unsigned short* woc,
    const void* bo, void* out, const int* __restrict__ dflag)
{
    const int isf32 = dflag[0];
    const unsigned short* W = isf32 ? woc : (const unsigned short*)wo;
    gemm_body(att, W, bo, out, D_MOD, D_MOD, isf32, isf32, 1.0f,
              blockIdx.y * 64, blockIdx.x * 128);
}

// ---------------------------------------------------------------------------
// Mask prepass: flags[b][qt][kt] = 1 iff any zero in the 64x64 mask tile.
// ---------------------------------------------------------------------------
__global__ __launch_bounds__(256) void mask_tiles(const int* __restrict__ mask,
                                                  int* __restrict__ flags)
{
    __shared__ int f;
    const int tid = threadIdx.x;
    if (tid == 0) f = 0;
    __syncthreads();
    const int b = blockIdx.z, qt = blockIdx.y, kt = blockIdx.x;
    const int* base = mask + (size_t)b * T_SEQ * T_SEQ
                    + (size_t)(qt * 64 + (tid >> 2)) * T_SEQ + kt * 64 + (tid & 3) * 16;
    int any = 0;
#pragma unroll
    for (int j = 0; j < 4; ++j) {
        int4v v = *(const int4v*)(base + j * 4);
        any |= (v.x == 0) | (v.y == 0) | (v.z == 0) | (v.w == 0);
    }
    if (any) f = 1;
    __syncthreads();
    if (tid == 0) flags[((size_t)b * 32 + qt) * 32 + kt] = f;
}

// ---------------------------------------------------------------------------
// V transpose: Vt[(b*16+h)*64 + d][t] = Vp[b*T+t][h*64+d]  (bf16)
// ---------------------------------------------------------------------------
__global__ __launch_bounds__(256) void vtrans(
    const unsigned short* __restrict__ Vp, unsigned short* __restrict__ Vt)
{
    __shared__ unsigned short s[64][72];
    const int tid = threadIdx.x;
    const int r0 = tid >> 3;
    const int c0 = (tid & 7) * 8;
    const int t0 = blockIdx.x * 64;
    const int h  = blockIdx.y, b = blockIdx.z;
    const size_t base = (size_t)b * T_SEQ * D_MOD + (size_t)h * 64;

    *(int4v*)&s[r0][c0]      = *(const int4v*)&Vp[base + (size_t)(t0 + r0) * D_MOD + c0];
    *(int4v*)&s[r0 + 32][c0] = *(const int4v*)&Vp[base + (size_t)(t0 + r0 + 32) * D_MOD + c0];
    __syncthreads();

    union { int4v v; unsigned short u[8]; } o0, o1;
#pragma unroll
    for (int j = 0; j < 8; ++j) { o0.u[j] = s[c0 + j][r0]; o1.u[j] = s[c0 + j][r0 + 32]; }
    const size_t ob = (size_t)(b * 16 + h) * 64;
    *(int4v*)&Vt[(ob + r0) * T_SEQ + t0 + c0]      = o0.v;
    *(int4v*)&Vt[(ob + r0 + 32) * T_SEQ + t0 + c0] = o1.v;
}

// ---------------------------------------------------------------------------
// Flash attention, 32x32 swapped-QK^T structure (unchanged from round 3).
// Block = 4 waves x 32 q-rows = 128 q; grid (16,16,2) = 512 blocks.
// ---------------------------------------------------------------------------
__global__ __launch_bounds__(256) void flash_attn(
    const unsigned short* __restrict__ Qp, const unsigned short* __restrict__ Kp,
    const unsigned short* __restrict__ Vt, const int* __restrict__ mask,
    const int* __restrict__ flags, unsigned short* __restrict__ att)
{
    __shared__ short sK[2][64][64];
    __shared__ short sV[2][64][64];     // [buf][d][k]

    const int tid = threadIdx.x;
    const int w   = tid >> 6;
    const int l   = tid & 63;
    const int lq  = l & 31;             // frag row / S column (this lane's q)
    const int hi  = l >> 5;
    const int lx  = lq & 7;             // read-side swizzle key
    const int b = blockIdx.z, h = blockIdx.y;
    const int q0 = blockIdx.x * 128;
    const int qw = q0 + w * 32;
    const int r0 = tid >> 3;            // staging row 0..31
    const int c0 = tid & 7;
    const int sc = c0 ^ (r0 & 7);       // pre-swizzled source chunk

    const size_t qkbase = (size_t)b * T_SEQ * D_MOD + (size_t)h * 64;
    const unsigned short* ksrc = Kp + qkbase + (size_t)r0 * D_MOD + sc * 8;
    const unsigned short* vsrc = Vt + ((size_t)((b * 16 + h) * 64) + r0) * T_SEQ + sc * 8;

#define STAGE_KV(buf, ktv)                                                        \
    {                                                                             \
        gload16(ksrc + (size_t)(ktv) * D_MOD,        &sK[buf][r0][c0 * 8]);       \
        gload16(ksrc + (size_t)((ktv) + 32) * D_MOD, &sK[buf][r0 + 32][c0 * 8]);  \
        gload16(vsrc + (ktv),                        &sV[buf][r0][c0 * 8]);       \
        gload16(vsrc + (size_t)32 * T_SEQ + (ktv),   &sV[buf][r0 + 32][c0 * 8]);  \
    }

    // Q fragments straight from global (L2-hot), B-layout: row lq, hd-slice
    frag8 qf[4];
    {
        const unsigned short* qrow = Qp + qkbase + (size_t)(qw + lq) * D_MOD + hi * 8;
#pragma unroll
        for (int ks = 0; ks < 4; ++ks)
            qf[ks] = *(const frag8*)(qrow + ks * 16);
    }

    STAGE_KV(0, 0);
    __syncthreads();

    float run_m = -1e30f, run_l = 0.f;
    f32x16 accO0 = {}, accO1 = {};

    const int* tfl = flags + ((size_t)b * 32 + (qw >> 6)) * 32;
    const int* mq  = mask + ((size_t)b * T_SEQ + qw + lq) * T_SEQ;

    int cur = 0;
    for (int kt = 0; kt < T_SEQ; kt += 64) {
        if (kt + 64 < T_SEQ) STAGE_KV(cur ^ 1, kt + 64);

        // ---- S^T = K Q^T : C[k][q], lane holds 32 S values of one q-row ----
        f32x16 s0 = {}, s1 = {};
        __builtin_amdgcn_s_setprio(1);
#pragma unroll
        for (int ks = 0; ks < 4; ++ks) {
            const int ch = ((ks * 2 + hi) ^ lx) * 8;
            frag8 k0 = *(const frag8*)&sK[cur][lq][ch];
            frag8 k1 = *(const frag8*)&sK[cur][32 + lq][ch];
            s0 = MFMA32(k0, qf[ks], s0);
            s1 = MFMA32(k1, qf[ks], s1);
        }
        __builtin_amdgcn_s_setprio(0);

        // ---- mask (slow path only) ----
        if (tfl[kt >> 6]) {
            const int* m0p = mq + kt;
#pragma unroll
            for (int r = 0; r < 16; ++r) {
                const int kof = (r & 3) + 8 * (r >> 2) + 4 * hi;
                if (m0p[kof] == 0)      s0[r] = -1e30f;
                if (m0p[32 + kof] == 0) s1[r] = -1e30f;
            }
        }

        // ---- tile max (in-lane tree + one cross-half exchange) ----
        float tm = s0[0];
#pragma unroll
        for (int r = 1; r < 16; ++r) tm = fmaxf(tm, s0[r]);
#pragma unroll
        for (int r = 0; r < 16; ++r) tm = fmaxf(tm, s1[r]);
        tm = fmaxf(tm, __shfl_xor(tm, 32, 64));

        // ---- defer-max rescale (rare after first tile) ----
        if (__any(tm > run_m + 8.0f)) {
            const float nm = fmaxf(run_m, tm);
            const float al = exp2_hw(run_m - nm);
            run_m = nm;
            run_l *= al;
            float alr[16];
#pragma unroll
            for (int r = 0; r < 16; ++r)
                alr[r] = __shfl(al, (r & 3) + 8 * (r >> 2) + 4 * hi, 64);
#pragma unroll
            for (int r = 0; r < 16; ++r) { accO0[r] *= alr[r]; accO1[r] *= alr[r]; }
        }

        // ---- exp2 + row sum ----
        float a0 = 0.f, a1 = 0.f, a2 = 0.f, a3 = 0.f;
#pragma unroll
        for (int r = 0; r < 16; r += 4) {
            s0[r]     = exp2_hw(s0[r]     - run_m);
            s0[r + 1] = exp2_hw(s0[r + 1] - run_m);
            s0[r + 2] = exp2_hw(s0[r + 2] - run_m);
            s0[r + 3] = exp2_hw(s0[r + 3] - run_m);
            s1[r]     = exp2_hw(s1[r]     - run_m);
            s1[r + 1] = exp2_hw(s1[r + 1] - run_m);
            s1[r + 2] = exp2_hw(s1[r + 2] - run_m);
            s1[r + 3] = exp2_hw(s1[r + 3] - run_m);
            a0 += s0[r]     + s1[r];
            a1 += s0[r + 1] + s1[r + 1];
            a2 += s0[r + 2] + s1[r + 2];
            a3 += s0[r + 3] + s1[r + 3];
        }
        float rs = (a0 + a1) + (a2 + a3);
        rs += __shfl_xor(rs, 32, 64);
        run_l += rs;

        // ---- P -> PV A-frags ----
        // C-layout gives (hi=0): s0[0..7] = k{0..3,8..11}; (hi=1): k{4..7,12..15}.
        // Pack pairs with cvt_pk, then exchange across the lane-32 halves so
        // each lane holds the A-frag k = ks*16 + hi*8 + {0..7}.
        union PU { frag8 f; unsigned u[4]; };
        PU pu0, pu1, pu2, pu3;
        pu0.u[0] = cvtpk(s0[0],  s0[1]);  pu0.u[1] = cvtpk(s0[2],  s0[3]);
        pu0.u[2] = cvtpk(s0[4],  s0[5]);  pu0.u[3] = cvtpk(s0[6],  s0[7]);
        pu1.u[0] = cvtpk(s0[8],  s0[9]);  pu1.u[1] = cvtpk(s0[10], s0[11]);
        pu1.u[2] = cvtpk(s0[12], s0[13]); pu1.u[3] = cvtpk(s0[14], s0[15]);
        pu2.u[0] = cvtpk(s1[0],  s1[1]);  pu2.u[1] = cvtpk(s1[2],  s1[3]);
        pu2.u[2] = cvtpk(s1[4],  s1[5]);  pu2.u[3] = cvtpk(s1[6],  s1[7]);
        pu3.u[0] = cvtpk(s1[8],  s1[9]);  pu3.u[1] = cvtpk(s1[10], s1[11]);
        pu3.u[2] = cvtpk(s1[12], s1[13]); pu3.u[3] = cvtpk(s1[14], s1[15]);
        xhalf(pu0.u[0], pu0.u[1], pu0.u[2], pu0.u[3], hi);
        xhalf(pu1.u[0], pu1.u[1], pu1.u[2], pu1.u[3], hi);
        xhalf(pu2.u[0], pu2.u[1], pu2.u[2], pu2.u[3], hi);
        xhalf(pu3.u[0], pu3.u[1], pu3.u[2], pu3.u[3], hi);
        frag8 pa[4] = { pu0.f, pu1.f, pu2.f, pu3.f };

        // ---- O += P V ----
        __builtin_amdgcn_s_setprio(1);
#pragma unroll
        for (int ks = 0; ks < 4; ++ks) {
            const int ch = ((ks * 2 + hi) ^ lx) * 8;
            frag8 v0 = *(const frag8*)&sV[cur][lq][ch];
            frag8 v1 = *(const frag8*)&sV[cur][32 + lq][ch];
            accO0 = MFMA32(pa[ks], v0, accO0);
            accO1 = MFMA32(pa[ks], v1, accO1);
        }
        __builtin_amdgcn_s_setprio(0);

        __syncthreads();   // drains prefetch; protects buffers
        cur ^= 1;
    }

    // ---- epilogue: O / l, gather per-row 1/l across lanes ----
    const float rinv = 1.0f / run_l;
    float rr[16];
#pragma unroll
    for (int r = 0; r < 16; ++r)
        rr[r] = __shfl(rinv, (r & 3) + 8 * (r >> 2) + 4 * hi, 64);
#pragma unroll
    for (int r = 0; r < 16; ++r) {
        const int qq = qw + (r & 3) + 8 * (r >> 2) + 4 * hi;
        unsigned short* orow = att + ((size_t)b * T_SEQ + qq) * D_MOD + h * 64 + lq;
        orow[0]  = (unsigned short)f2bf(accO0[r] * rr[r]);
        orow[32] = (unsigned short)f2bf(accO1[r] * rr[r]);
    }
#undef STAGE_KV
}

// ---------------------------------------------------------------------------
extern "C" void kernel_launch(void* const* d_in, const int* in_sizes, int n_in,
                              void* d_out, int out_size, void* d_ws, size_t ws_size,
                              hipStream_t stream) {
    const void* query = d_in[0];
    const void* key   = d_in[1];
    const void* value = d_in[2];
    const int*  mask  = (const int*)d_in[3];
    const void* wq = d_in[4];
    const void* bq = d_in[5];
    const void* wk = d_in[6];
    const void* bk = d_in[7];
    const void* wv = d_in[8];
    const void* bv = d_in[9];
    const void* wo = d_in[10];
    const void* bo = d_in[11];

    const int Mtot = 2 * T_SEQ;              // 4096
    const size_t MD = (size_t)Mtot * D_MOD;  // 4M elems
    const size_t WW = (size_t)D_MOD * D_MOD; // 1M elems

    unsigned short* Xq  = (unsigned short*)d_ws;  // converted query; reused as Vt
    unsigned short* Xk  = Xq + MD;
    unsigned short* Xv  = Xk + MD;
    unsigned short* Wqb = Xv + MD;
    unsigned short* Wkb = Wqb + WW;
    unsigned short* Wvb = Wkb + WW;
    unsigned short* Wob = Wvb + WW;
    unsigned short* Qp  = Wob + WW;
    unsigned short* Kp  = Qp + MD;
    unsigned short* Vp  = Kp + MD;
    unsigned short* Vt  = Xq;                // alias: Xq dead after Q GEMM
    unsigned short* att = Vp;                // alias: Vp dead after vtrans
    int* flags          = (int*)(Vp + MD);   // 2048 ints
    int* dflag          = flags + 2048;

    const dim3 blk(256);

    detect_dtype<<<1, 64, 0, stream>>>((const unsigned short*)query, dflag);

    cvt_x<<<dim3(2048, 3), blk, 0, stream>>>(
        (const float*)query, (const float*)key, (const float*)value, Xq, Xk, Xv, dflag);
    cvt_w<<<dim3(512, 4), blk, 0, stream>>>(
        (const float*)wq, (const float*)wk, (const float*)wv, (const float*)wo,
        Wqb, Wkb, Wvb, Wob, dflag);
    mask_tiles<<<dim3(32, 32, 2), blk, 0, stream>>>(mask, flags);

    gemm_qkv<<<dim3(D_MOD / 128, Mtot / 64, 3), blk, 0, stream>>>(
        query, Xq, key, Xk, value, Xv,
        wq, Wqb, wk, Wkb, wv, Wvb,
        bq, bk, bv, Qp, Kp, Vp, dflag);

    vtrans<<<dim3(32, 16, 2), blk, 0, stream>>>(Vp, Vt);

    flash_attn<<<dim3(T_SEQ / 128, 16, 2), blk, 0, stream>>>(Qp, Kp, Vt, mask, flags, att);

    gemm_out<<<dim3(D_MOD / 128, Mtot / 64), blk, 0, stream>>>(
        att, wo, Wob, bo, d_out, dflag);
}